// Round 1
// 478.458 us; speedup vs baseline: 1.1022x; 1.1022x over previous
//
#include <hip/hip_runtime.h>
#include <hip/hip_bf16.h>
#include <math.h>

#define N_NODES 100000
#define N_EDGES 3200000
#define DIM_IN  128
#define DIM_HID 64
#define DIM_OUT 40

#define SBSHIFT 8
#define SBNODES 256                                  // nodes per super-bucket
#define NSB ((N_NODES + SBNODES - 1) / SBNODES)      // 391
#define HPAD  16                                     // counter stride: 64 B
#define CHUNK 8192
#define NCHUNK ((N_EDGES + CHUNK - 1) / CHUNK)       // 391

typedef int v2i  __attribute__((ext_vector_type(2)));
typedef int v16i __attribute__((ext_vector_type(16)));

// ---- hist: per-WG LDS histogram of dst>>8, flushed to padded global counters
__global__ __launch_bounds__(256) void hist_kernel(
    const int* __restrict__ dst, int* __restrict__ hist) {
  __shared__ int cnt[NSB];
  const int t = threadIdx.x;
  for (int i = t; i < NSB; i += 256) cnt[i] = 0;
  __syncthreads();
  const int e0 = blockIdx.x * CHUNK;
  const int e1 = min(e0 + CHUNK, N_EDGES);
  for (int e = e0 + t; e < e1; e += 256) atomicAdd(&cnt[dst[e] >> SBSHIFT], 1);
  __syncthreads();
  for (int i = t; i < NSB; i += 256) {
    const int c = cnt[i];
    if (c) atomicAdd(&hist[i * HPAD], c);
  }
}

// ---- exclusive scan of 391 super-bucket counts (single block) --------------
__global__ __launch_bounds__(256) void scanb_kernel(
    const int* __restrict__ hist, int* __restrict__ base,
    int* __restrict__ cursor, int* __restrict__ ptr) {
  const int t = threadIdx.x;
  const int i0 = 2 * t, i1 = 2 * t + 1;
  const int v0 = (i0 < NSB) ? hist[i0 * HPAD] : 0;
  const int v1 = (i1 < NSB) ? hist[i1 * HPAD] : 0;
  const int s = v0 + v1;
  const int lane = t & 63, wid = t >> 6;
  int incl = s;
#pragma unroll
  for (int off = 1; off < 64; off <<= 1) {
    int n = __shfl_up(incl, off);
    if (lane >= off) incl += n;
  }
  __shared__ int wsum[4];
  if (lane == 63) wsum[wid] = incl;
  __syncthreads();
  int woff = 0;
  for (int k = 0; k < wid; ++k) woff += wsum[k];
  int run = woff + incl - s;
  if (i0 < NSB) { base[i0] = run; cursor[i0 * HPAD] = run; }
  run += v0;
  if (i1 < NSB) { base[i1] = run; cursor[i1 * HPAD] = run; }
  if (t == 255) { base[NSB] = N_EDGES; ptr[N_NODES] = N_EDGES; }
}

// ---- scatter pass 1: edges -> super-bucket regions, per-WG LDS reservation -
__global__ __launch_bounds__(256) void scatter_kernel(
    const int* __restrict__ dst, const int* __restrict__ src,
    const float* __restrict__ ew, int* __restrict__ cursor,
    int2* __restrict__ packed1) {
  __shared__ int cnt[NSB];
  const int t = threadIdx.x;
  for (int i = t; i < NSB; i += 256) cnt[i] = 0;
  __syncthreads();
  const int e0 = blockIdx.x * CHUNK;
  const int e1 = min(e0 + CHUNK, N_EDGES);
  for (int e = e0 + t; e < e1; e += 256) atomicAdd(&cnt[dst[e] >> SBSHIFT], 1);
  __syncthreads();
  for (int i = t; i < NSB; i += 256) {
    const int c = cnt[i];
    cnt[i] = c ? atomicAdd(&cursor[i * HPAD], c) : 0;  // cnt becomes cursor
  }
  __syncthreads();
  for (int e = e0 + t; e < e1; e += 256) {
    const int d = dst[e];
    const int pos = atomicAdd(&cnt[d >> SBSHIFT], 1);
    int2 q;
    q.x = ((d & (SBNODES - 1)) << 20) | src[e];   // src < 2^20, dstLow8 @20
    q.y = __float_as_int(ew[e]);
    packed1[pos] = q;
  }
}

// ---- pass 2: sort each super-bucket to node order; emit ptr ---------------
// packed2.x now stores src*128 (byte offset of the 128-B bf16 row) so the
// SPMM scalar address math is just a 64-bit add.
__global__ __launch_bounds__(256) void sortsb_kernel(
    const int* __restrict__ base, const int2* __restrict__ packed1,
    int2* __restrict__ packed2, int* __restrict__ ptr) {
  __shared__ int cnt[SBNODES];
  __shared__ int cur[SBNODES];
  __shared__ int wsum[4];
  const int t = threadIdx.x;
  const int b = blockIdx.x;
  cnt[t] = 0;
  const int e0 = base[b], e1 = base[b + 1];
  __syncthreads();
  for (int e = e0 + t; e < e1; e += 256)
    atomicAdd(&cnt[(packed1[e].x >> 20) & (SBNODES - 1)], 1);
  __syncthreads();
  const int lane = t & 63, wid = t >> 6;
  const int v = cnt[t];
  int incl = v;
#pragma unroll
  for (int off = 1; off < 64; off <<= 1) {
    int n = __shfl_up(incl, off);
    if (lane >= off) incl += n;
  }
  if (lane == 63) wsum[wid] = incl;
  __syncthreads();
  int woff = 0;
  for (int k = 0; k < wid; ++k) woff += wsum[k];
  const int start = e0 + woff + incl - v;
  cur[t] = start;
  const int node = (b << SBSHIFT) + t;
  if (node < N_NODES) ptr[node] = start;
  __syncthreads();
  for (int e = e0 + t; e < e1; e += 256) {
    const int2 p = packed1[e];
    const int pos = atomicAdd(&cur[(p.x >> 20) & (SBNODES - 1)], 1);
    int2 q; q.x = (p.x & 0xFFFFF) << 7; q.y = p.y;   // byte offset of row
    packed2[pos] = q;
  }
}

// ---- GEMM1: h = x @ W1 (bf16 out), 16 rows/block -------------------------
__global__ __launch_bounds__(256) void gemm1_kernel(
    const float* __restrict__ x, const float* __restrict__ W1,
    __hip_bfloat16* __restrict__ h) {
  __shared__ float w[DIM_IN * DIM_HID];   // 32 KB
  for (int i = threadIdx.x; i < DIM_IN * DIM_HID; i += 256) w[i] = W1[i];
  __syncthreads();
  const int lane = threadIdx.x & 63, wid = threadIdx.x >> 6;
#pragma unroll
  for (int r = 0; r < 4; ++r) {
    const int row = blockIdx.x * 16 + r * 4 + wid;   // 100000 % 16 == 0
    const float4* xr = (const float4*)(x + (size_t)row * DIM_IN);
    float acc = 0.f;
#pragma unroll 8
    for (int k4 = 0; k4 < DIM_IN / 4; ++k4) {
      const float4 xv = xr[k4];
      acc = fmaf(xv.x, w[(k4 * 4 + 0) * DIM_HID + lane], acc);
      acc = fmaf(xv.y, w[(k4 * 4 + 1) * DIM_HID + lane], acc);
      acc = fmaf(xv.z, w[(k4 * 4 + 2) * DIM_HID + lane], acc);
      acc = fmaf(xv.w, w[(k4 * 4 + 3) * DIM_HID + lane], acc);
    }
    h[(size_t)row * DIM_HID + lane] = __float2bfloat16(acc);
  }
}

// ---- SPMM: one wave per node, one dim per lane, scalar edge data -----------
// Edge (src_byte_off, wgt) pairs are wave-uniform -> s_load into SGPRs.
// Per edge per lane: 1 ushort gather (saddr + fixed voffset), 1 shift, 1 fmac
// with the weight as SGPR operand. Tail edges are neutralized with scalar
// cselect (wgt=0, off=0); packed2 is padded so the s_load never faults.
template <int RELU>
__global__ __launch_bounds__(256) void spmm_kernel(
    const int* __restrict__ ptr, const int2* __restrict__ packed,
    const char* __restrict__ hsrc, unsigned short* __restrict__ hout) {
  const int wv = __builtin_amdgcn_readfirstlane(threadIdx.x) >> 6;  // scalar
  const int node = blockIdx.x * 4 + wv;                 // 25000*4 == N
  const int lane = threadIdx.x & 63;
  v2i pp;
  asm volatile("s_load_dwordx2 %0, %1, 0x0\n\ts_waitcnt lgkmcnt(0)"
               : "=s"(pp) : "s"(ptr + node));
  const int eb = pp[0];
  const int deg = pp[1] - pp[0];
  const int2* pk = packed + eb;
  float acc = 0.f;
  int i = 0;
  for (; i + 8 <= deg; i += 8) {
    v16i q;
    asm volatile("s_load_dwordx16 %0, %1, 0x0\n\ts_waitcnt lgkmcnt(0)"
                 : "=s"(q) : "s"(pk + i));
#pragma unroll
    for (int j = 0; j < 8; ++j) {
      const unsigned short* rp =
          (const unsigned short*)(hsrc + (unsigned)q[2 * j]);
      const float wgt = __int_as_float(q[2 * j + 1]);
      acc = fmaf(wgt, __uint_as_float((unsigned)rp[lane] << 16), acc);
    }
  }
  if (i < deg) {                       // one predicated tail block (scalar)
    v16i q;
    asm volatile("s_load_dwordx16 %0, %1, 0x0\n\ts_waitcnt lgkmcnt(0)"
                 : "=s"(q) : "s"(pk + i));
#pragma unroll
    for (int j = 0; j < 8; ++j) {
      const bool val = (i + j) < deg;
      const int off = val ? q[2 * j] : 0;
      const float wgt = val ? __int_as_float(q[2 * j + 1]) : 0.f;
      const unsigned short* rp = (const unsigned short*)(hsrc + (unsigned)off);
      acc = fmaf(wgt, __uint_as_float((unsigned)rp[lane] << 16), acc);
    }
  }
  if (RELU) acc = fmaxf(acc, 0.f);
  const unsigned u = __float_as_uint(acc);
  const unsigned r = (u + 0x7FFFu + ((u >> 16) & 1u)) >> 16;   // RNE to bf16
  hout[((size_t)node << 6) + lane] = (unsigned short)r;
}

// ---- final: out = log_softmax(agg2 @ W2), one node per thread --------------
// (A @ (R@W2) == (A@R) @ W2 -- associativity moved W2 after the 2nd SPMM.)
__global__ __launch_bounds__(256) void gemm2_lsm_kernel(
    const __hip_bfloat16* __restrict__ agg2, const float* __restrict__ W2,
    float* __restrict__ out) {
  __shared__ float w2[DIM_HID * DIM_OUT];   // 10 KB, [k][c]
  for (int i = threadIdx.x; i < DIM_HID * DIM_OUT; i += 256) w2[i] = W2[i];
  __syncthreads();
  const int node = blockIdx.x * 256 + threadIdx.x;
  if (node >= N_NODES) return;
  const int4* rp = (const int4*)(agg2 + (size_t)node * 64);
  float sc[DIM_OUT];
#pragma unroll
  for (int c = 0; c < DIM_OUT; ++c) sc[c] = 0.f;
#pragma unroll
  for (int t = 0; t < 8; ++t) {
    const int4 v = rp[t];                       // 8 bf16 of the row
    const unsigned uu[4] = {(unsigned)v.x, (unsigned)v.y,
                            (unsigned)v.z, (unsigned)v.w};
#pragma unroll
    for (int p = 0; p < 4; ++p) {
      const float f0 = __uint_as_float(uu[p] << 16);
      const float f1 = __uint_as_float(uu[p] & 0xFFFF0000u);
      const int k = t * 8 + p * 2;
      const float4* wa = (const float4*)&w2[k * DIM_OUT];        // broadcast
      const float4* wb = (const float4*)&w2[(k + 1) * DIM_OUT];  // broadcast
#pragma unroll
      for (int q4 = 0; q4 < DIM_OUT / 4; ++q4) {
        const float4 a = wa[q4], b = wb[q4];
        sc[4 * q4 + 0] = fmaf(f0, a.x, fmaf(f1, b.x, sc[4 * q4 + 0]));
        sc[4 * q4 + 1] = fmaf(f0, a.y, fmaf(f1, b.y, sc[4 * q4 + 1]));
        sc[4 * q4 + 2] = fmaf(f0, a.z, fmaf(f1, b.z, sc[4 * q4 + 2]));
        sc[4 * q4 + 3] = fmaf(f0, a.w, fmaf(f1, b.w, sc[4 * q4 + 3]));
      }
    }
  }
  float m = sc[0];
#pragma unroll
  for (int c = 1; c < DIM_OUT; ++c) m = fmaxf(m, sc[c]);
  float s = 0.f;
#pragma unroll
  for (int c = 0; c < DIM_OUT; ++c) s += __expf(sc[c] - m);
  const float ls = __logf(s) + m;
  float4* op = (float4*)(out + (size_t)node * DIM_OUT);
#pragma unroll
  for (int t = 0; t < DIM_OUT / 4; ++t) {
    float4 o;
    o.x = sc[4 * t + 0] - ls;
    o.y = sc[4 * t + 1] - ls;
    o.z = sc[4 * t + 2] - ls;
    o.w = sc[4 * t + 3] - ls;
    op[t] = o;
  }
}

extern "C" void kernel_launch(void* const* d_in, const int* in_sizes, int n_in,
                              void* d_out, int out_size, void* d_ws, size_t ws_size,
                              hipStream_t stream) {
  const float* x  = (const float*)d_in[0];
  const int*   ei = (const int*)d_in[1];   // [2, E]: first E = dst, next E = src
  const float* ew = (const float*)d_in[2];
  const float* W1 = (const float*)d_in[3];
  const float* W2 = (const float*)d_in[4];
  float* out = (float*)d_out;

  const int* dst = ei;
  const int* src = ei + N_EDGES;

  // ---- workspace layout (regions reused once dead) ----
  // region0: packed1 (build) -> h_agg bf16 [N][64] (after sortsb)
  // region1: packed2 (+pad)
  // region2: h bf16 [N][64] (gemm1 out) -> agg2 bf16 [N][64] (after spmm1)
  char* p = (char*)d_ws;
  int2*           packed1 = (int2*)p;
  unsigned short* h_agg   = (unsigned short*)p;   // 12.8 MB of the 25.6
  p += (size_t)N_EDGES * 8;                                     // 25.6 MB
  int2* packed2 = (int2*)p;  p += (size_t)(N_EDGES + 16) * 8;   // 25.6 MB + pad
  __hip_bfloat16* h = (__hip_bfloat16*)p;
  unsigned short* agg2 = (unsigned short*)p;      // reuses h after spmm1
  p += (size_t)N_NODES * DIM_HID * 2;                           // 12.8 MB
  int* hist   = (int*)p;  p += (size_t)NSB * HPAD * 4;          // 25 KB
  int* cursor = (int*)p;  p += (size_t)NSB * HPAD * 4;          // 25 KB
  int* base   = (int*)p;  p += (size_t)(NSB + 8) * 4;
  int* ptr    = (int*)p;  p += (size_t)(N_NODES + 8) * 4;       // 400 KB

  // ---- build: sb hist -> scan -> sb scatter -> in-sb node sort ----
  hipMemsetAsync(hist, 0, (size_t)NSB * HPAD * 4, stream);
  hist_kernel<<<NCHUNK, 256, 0, stream>>>(dst, hist);
  scanb_kernel<<<1, 256, 0, stream>>>(hist, base, cursor, ptr);
  scatter_kernel<<<NCHUNK, 256, 0, stream>>>(dst, src, ew, cursor, packed1);
  sortsb_kernel<<<NSB, 256, 0, stream>>>(base, packed1, packed2, ptr);

  // ---- layer 1 GEMM (bf16 h) ----
  gemm1_kernel<<<N_NODES / 16, 256, 0, stream>>>(x, W1, h);

  // ---- SPMM1: h_agg = relu(A @ h)  (h_agg overwrites dead packed1) ----
  spmm_kernel<1><<<N_NODES / 4, 256, 0, stream>>>(
      ptr, packed2, (const char*)h, h_agg);

  // ---- SPMM2: agg2 = A @ h_agg  (agg2 overwrites dead h) ----
  spmm_kernel<0><<<N_NODES / 4, 256, 0, stream>>>(
      ptr, packed2, (const char*)h_agg, agg2);

  // ---- out = log_softmax(agg2 @ W2) ----
  gemm2_lsm_kernel<<<(N_NODES + 255) / 256, 256, 0, stream>>>(
      (const __hip_bfloat16*)agg2, W2, out);
}

// Round 2
// 384.265 us; speedup vs baseline: 1.3724x; 1.2451x over previous
//
#include <hip/hip_runtime.h>
#include <hip/hip_bf16.h>
#include <math.h>

#define N_NODES 100000
#define N_EDGES 3200000
#define DIM_IN  128
#define DIM_HID 64
#define DIM_OUT 40

#define SBSHIFT 8
#define SBNODES 256                                  // nodes per super-bucket
#define NSB ((N_NODES + SBNODES - 1) / SBNODES)      // 391
#define HPAD  16                                     // counter stride: 64 B
#define CHUNK 8192
#define NCHUNK ((N_EDGES + CHUNK - 1) / CHUNK)       // 391
#define GRID1 512                                    // gemm1 blocks

typedef int v2i  __attribute__((ext_vector_type(2)));
typedef int v16i __attribute__((ext_vector_type(16)));
typedef short bf16x8 __attribute__((ext_vector_type(8)));
typedef float f32x4  __attribute__((ext_vector_type(4)));

__device__ inline unsigned short f32_to_bf16_rne(float f) {
  const unsigned u = __float_as_uint(f);
  return (unsigned short)((u + 0x7FFFu + ((u >> 16) & 1u)) >> 16);
}

// ---- hist: per-WG LDS histogram of dst>>8, flushed to padded global counters
__global__ __launch_bounds__(256) void hist_kernel(
    const int* __restrict__ dst, int* __restrict__ hist) {
  __shared__ int cnt[NSB];
  const int t = threadIdx.x;
  for (int i = t; i < NSB; i += 256) cnt[i] = 0;
  __syncthreads();
  const int e0 = blockIdx.x * CHUNK;
  const int e1 = min(e0 + CHUNK, N_EDGES);
  for (int e = e0 + t; e < e1; e += 256) atomicAdd(&cnt[dst[e] >> SBSHIFT], 1);
  __syncthreads();
  for (int i = t; i < NSB; i += 256) {
    const int c = cnt[i];
    if (c) atomicAdd(&hist[i * HPAD], c);
  }
}

// ---- exclusive scan of 391 super-bucket counts (single block) --------------
__global__ __launch_bounds__(256) void scanb_kernel(
    const int* __restrict__ hist, int* __restrict__ base,
    int* __restrict__ cursor, int* __restrict__ ptr) {
  const int t = threadIdx.x;
  const int i0 = 2 * t, i1 = 2 * t + 1;
  const int v0 = (i0 < NSB) ? hist[i0 * HPAD] : 0;
  const int v1 = (i1 < NSB) ? hist[i1 * HPAD] : 0;
  const int s = v0 + v1;
  const int lane = t & 63, wid = t >> 6;
  int incl = s;
#pragma unroll
  for (int off = 1; off < 64; off <<= 1) {
    int n = __shfl_up(incl, off);
    if (lane >= off) incl += n;
  }
  __shared__ int wsum[4];
  if (lane == 63) wsum[wid] = incl;
  __syncthreads();
  int woff = 0;
  for (int k = 0; k < wid; ++k) woff += wsum[k];
  int run = woff + incl - s;
  if (i0 < NSB) { base[i0] = run; cursor[i0 * HPAD] = run; }
  run += v0;
  if (i1 < NSB) { base[i1] = run; cursor[i1 * HPAD] = run; }
  if (t == 255) { base[NSB] = N_EDGES; ptr[N_NODES] = N_EDGES; }
}

// ---- scatter pass 1: edges -> super-bucket regions, per-WG LDS reservation -
__global__ __launch_bounds__(256) void scatter_kernel(
    const int* __restrict__ dst, const int* __restrict__ src,
    const float* __restrict__ ew, int* __restrict__ cursor,
    int2* __restrict__ packed1) {
  __shared__ int cnt[NSB];
  const int t = threadIdx.x;
  for (int i = t; i < NSB; i += 256) cnt[i] = 0;
  __syncthreads();
  const int e0 = blockIdx.x * CHUNK;
  const int e1 = min(e0 + CHUNK, N_EDGES);
  for (int e = e0 + t; e < e1; e += 256) atomicAdd(&cnt[dst[e] >> SBSHIFT], 1);
  __syncthreads();
  for (int i = t; i < NSB; i += 256) {
    const int c = cnt[i];
    cnt[i] = c ? atomicAdd(&cursor[i * HPAD], c) : 0;  // cnt becomes cursor
  }
  __syncthreads();
  for (int e = e0 + t; e < e1; e += 256) {
    const int d = dst[e];
    const int pos = atomicAdd(&cnt[d >> SBSHIFT], 1);
    int2 q;
    q.x = ((d & (SBNODES - 1)) << 20) | src[e];   // src < 2^20, dstLow8 @20
    q.y = __float_as_int(ew[e]);
    packed1[pos] = q;
  }
}

// ---- pass 2: sort each super-bucket to node order; emit ptr ---------------
// packed2.x stores src*128 (byte offset of the 128-B bf16 row).
__global__ __launch_bounds__(256) void sortsb_kernel(
    const int* __restrict__ base, const int2* __restrict__ packed1,
    int2* __restrict__ packed2, int* __restrict__ ptr) {
  __shared__ int cnt[SBNODES];
  __shared__ int cur[SBNODES];
  __shared__ int wsum[4];
  const int t = threadIdx.x;
  const int b = blockIdx.x;
  cnt[t] = 0;
  const int e0 = base[b], e1 = base[b + 1];
  __syncthreads();
  for (int e = e0 + t; e < e1; e += 256)
    atomicAdd(&cnt[(packed1[e].x >> 20) & (SBNODES - 1)], 1);
  __syncthreads();
  const int lane = t & 63, wid = t >> 6;
  const int v = cnt[t];
  int incl = v;
#pragma unroll
  for (int off = 1; off < 64; off <<= 1) {
    int n = __shfl_up(incl, off);
    if (lane >= off) incl += n;
  }
  if (lane == 63) wsum[wid] = incl;
  __syncthreads();
  int woff = 0;
  for (int k = 0; k < wid; ++k) woff += wsum[k];
  const int start = e0 + woff + incl - v;
  cur[t] = start;
  const int node = (b << SBSHIFT) + t;
  if (node < N_NODES) ptr[node] = start;
  __syncthreads();
  for (int e = e0 + t; e < e1; e += 256) {
    const int2 p = packed1[e];
    const int pos = atomicAdd(&cur[(p.x >> 20) & (SBNODES - 1)], 1);
    int2 q; q.x = (p.x & 0xFFFFF) << 7; q.y = p.y;   // byte offset of row
    packed2[pos] = q;
  }
}

// ---- GEMM1 via MFMA: h = bf16(x @ W1) -------------------------------------
// One wave per 16-row tile (grid-strided). W1 staged to LDS once per block;
// each wave builds its 16 B-frags once (64 VGPRs) and loops tiles.
// A/B use the same (lane>>4)*8+j k-map for both operands (any consistent
// k-permutation is correct); C/D map is col=lane&15, row=(lane>>4)*4+reg.
__global__ __launch_bounds__(256) void gemm1_mfma_kernel(
    const float* __restrict__ x, const float* __restrict__ W1,
    unsigned short* __restrict__ h) {
  __shared__ float wlds[DIM_IN * DIM_HID];   // 32 KB
  for (int i = threadIdx.x; i < DIM_IN * DIM_HID; i += 256) wlds[i] = W1[i];
  __syncthreads();
  const int lane = threadIdx.x & 63;
  const int wid = threadIdx.x >> 6;
  const int r16 = lane & 15;    // A row / B col within tile
  const int kg = lane >> 4;     // k-group of 8

  bf16x8 bf[4][4];              // [kc][nt]
#pragma unroll
  for (int kc = 0; kc < 4; ++kc)
#pragma unroll
    for (int nt = 0; nt < 4; ++nt)
#pragma unroll
      for (int j = 0; j < 8; ++j)
        bf[kc][nt][j] = (short)f32_to_bf16_rne(
            wlds[(kc * 32 + kg * 8 + j) * DIM_HID + nt * 16 + r16]);

  const int wglobal = blockIdx.x * 4 + wid;
  for (int tile = wglobal; tile < N_NODES / 16; tile += GRID1 * 4) {
    const float* xr = x + (size_t)(tile * 16 + r16) * DIM_IN + kg * 8;
    bf16x8 af[4];
#pragma unroll
    for (int kc = 0; kc < 4; ++kc) {
      const float4 v0 = *(const float4*)(xr + kc * 32);
      const float4 v1 = *(const float4*)(xr + kc * 32 + 4);
      af[kc][0] = (short)f32_to_bf16_rne(v0.x);
      af[kc][1] = (short)f32_to_bf16_rne(v0.y);
      af[kc][2] = (short)f32_to_bf16_rne(v0.z);
      af[kc][3] = (short)f32_to_bf16_rne(v0.w);
      af[kc][4] = (short)f32_to_bf16_rne(v1.x);
      af[kc][5] = (short)f32_to_bf16_rne(v1.y);
      af[kc][6] = (short)f32_to_bf16_rne(v1.z);
      af[kc][7] = (short)f32_to_bf16_rne(v1.w);
    }
    f32x4 acc[4];
#pragma unroll
    for (int nt = 0; nt < 4; ++nt) acc[nt] = (f32x4){0.f, 0.f, 0.f, 0.f};
#pragma unroll
    for (int kc = 0; kc < 4; ++kc)
#pragma unroll
      for (int nt = 0; nt < 4; ++nt)
        acc[nt] = __builtin_amdgcn_mfma_f32_16x16x32_bf16(
            af[kc], bf[kc][nt], acc[nt], 0, 0, 0);
    unsigned short* hr = h + (size_t)tile * 16 * DIM_HID;
#pragma unroll
    for (int nt = 0; nt < 4; ++nt)
#pragma unroll
      for (int r = 0; r < 4; ++r)
        hr[(kg * 4 + r) * DIM_HID + nt * 16 + r16] = f32_to_bf16_rne(acc[nt][r]);
  }
}

// ---- SPMM: one wave per node, one dim per lane, scalar edge data -----------
template <int RELU>
__global__ __launch_bounds__(256) void spmm_kernel(
    const int* __restrict__ ptr, const int2* __restrict__ packed,
    const char* __restrict__ hsrc, unsigned short* __restrict__ hout) {
  const int wv = __builtin_amdgcn_readfirstlane(threadIdx.x) >> 6;  // scalar
  const int node = blockIdx.x * 4 + wv;                 // 25000*4 == N
  const int lane = threadIdx.x & 63;
  v2i pp;
  asm volatile("s_load_dwordx2 %0, %1, 0x0\n\ts_waitcnt lgkmcnt(0)"
               : "=s"(pp) : "s"(ptr + node));
  const int eb = pp[0];
  const int deg = pp[1] - pp[0];
  const int2* pk = packed + eb;
  float acc = 0.f;
  int i = 0;
  for (; i + 8 <= deg; i += 8) {
    v16i q;
    asm volatile("s_load_dwordx16 %0, %1, 0x0\n\ts_waitcnt lgkmcnt(0)"
                 : "=s"(q) : "s"(pk + i));
#pragma unroll
    for (int j = 0; j < 8; ++j) {
      const unsigned short* rp =
          (const unsigned short*)(hsrc + (unsigned)q[2 * j]);
      const float wgt = __int_as_float(q[2 * j + 1]);
      acc = fmaf(wgt, __uint_as_float((unsigned)rp[lane] << 16), acc);
    }
  }
  if (i < deg) {                       // one predicated tail block (scalar)
    v16i q;
    asm volatile("s_load_dwordx16 %0, %1, 0x0\n\ts_waitcnt lgkmcnt(0)"
                 : "=s"(q) : "s"(pk + i));
#pragma unroll
    for (int j = 0; j < 8; ++j) {
      const bool val = (i + j) < deg;
      const int off = val ? q[2 * j] : 0;
      const float wgt = val ? __int_as_float(q[2 * j + 1]) : 0.f;
      const unsigned short* rp = (const unsigned short*)(hsrc + (unsigned)off);
      acc = fmaf(wgt, __uint_as_float((unsigned)rp[lane] << 16), acc);
    }
  }
  if (RELU) acc = fmaxf(acc, 0.f);
  hout[((size_t)node << 6) + lane] = f32_to_bf16_rne(acc);
}

// ---- final: out = log_softmax(agg2 @ W2), one node per thread --------------
__global__ __launch_bounds__(256) void gemm2_lsm_kernel(
    const __hip_bfloat16* __restrict__ agg2, const float* __restrict__ W2,
    float* __restrict__ out) {
  __shared__ float w2[DIM_HID * DIM_OUT];   // 10 KB, [k][c]
  for (int i = threadIdx.x; i < DIM_HID * DIM_OUT; i += 256) w2[i] = W2[i];
  __syncthreads();
  const int node = blockIdx.x * 256 + threadIdx.x;
  if (node >= N_NODES) return;
  const int4* rp = (const int4*)(agg2 + (size_t)node * 64);
  float sc[DIM_OUT];
#pragma unroll
  for (int c = 0; c < DIM_OUT; ++c) sc[c] = 0.f;
#pragma unroll
  for (int t = 0; t < 8; ++t) {
    const int4 v = rp[t];                       // 8 bf16 of the row
    const unsigned uu[4] = {(unsigned)v.x, (unsigned)v.y,
                            (unsigned)v.z, (unsigned)v.w};
#pragma unroll
    for (int p = 0; p < 4; ++p) {
      const float f0 = __uint_as_float(uu[p] << 16);
      const float f1 = __uint_as_float(uu[p] & 0xFFFF0000u);
      const int k = t * 8 + p * 2;
      const float4* wa = (const float4*)&w2[k * DIM_OUT];        // broadcast
      const float4* wb = (const float4*)&w2[(k + 1) * DIM_OUT];  // broadcast
#pragma unroll
      for (int q4 = 0; q4 < DIM_OUT / 4; ++q4) {
        const float4 a = wa[q4], b = wb[q4];
        sc[4 * q4 + 0] = fmaf(f0, a.x, fmaf(f1, b.x, sc[4 * q4 + 0]));
        sc[4 * q4 + 1] = fmaf(f0, a.y, fmaf(f1, b.y, sc[4 * q4 + 1]));
        sc[4 * q4 + 2] = fmaf(f0, a.z, fmaf(f1, b.z, sc[4 * q4 + 2]));
        sc[4 * q4 + 3] = fmaf(f0, a.w, fmaf(f1, b.w, sc[4 * q4 + 3]));
      }
    }
  }
  float m = sc[0];
#pragma unroll
  for (int c = 1; c < DIM_OUT; ++c) m = fmaxf(m, sc[c]);
  float s = 0.f;
#pragma unroll
  for (int c = 0; c < DIM_OUT; ++c) s += __expf(sc[c] - m);
  const float ls = __logf(s) + m;
  float4* op = (float4*)(out + (size_t)node * DIM_OUT);
#pragma unroll
  for (int t = 0; t < DIM_OUT / 4; ++t) {
    float4 o;
    o.x = sc[4 * t + 0] - ls;
    o.y = sc[4 * t + 1] - ls;
    o.z = sc[4 * t + 2] - ls;
    o.w = sc[4 * t + 3] - ls;
    op[t] = o;
  }
}

extern "C" void kernel_launch(void* const* d_in, const int* in_sizes, int n_in,
                              void* d_out, int out_size, void* d_ws, size_t ws_size,
                              hipStream_t stream) {
  const float* x  = (const float*)d_in[0];
  const int*   ei = (const int*)d_in[1];   // [2, E]: first E = dst, next E = src
  const float* ew = (const float*)d_in[2];
  const float* W1 = (const float*)d_in[3];
  const float* W2 = (const float*)d_in[4];
  float* out = (float*)d_out;

  const int* dst = ei;
  const int* src = ei + N_EDGES;

  // ---- workspace layout (regions reused once dead) ----
  // region0: packed1 (build) -> h_agg bf16 [N][64] (after sortsb)
  // region1: packed2 (+pad)
  // region2: h bf16 [N][64] (gemm1 out) -> agg2 bf16 [N][64] (after spmm1)
  char* p = (char*)d_ws;
  int2*           packed1 = (int2*)p;
  unsigned short* h_agg   = (unsigned short*)p;   // 12.8 MB of the 25.6
  p += (size_t)N_EDGES * 8;                                     // 25.6 MB
  int2* packed2 = (int2*)p;  p += (size_t)(N_EDGES + 16) * 8;   // 25.6 MB + pad
  unsigned short* h = (unsigned short*)p;
  unsigned short* agg2 = (unsigned short*)p;      // reuses h after spmm1
  p += (size_t)N_NODES * DIM_HID * 2;                           // 12.8 MB
  int* hist   = (int*)p;  p += (size_t)NSB * HPAD * 4;          // 25 KB
  int* cursor = (int*)p;  p += (size_t)NSB * HPAD * 4;          // 25 KB
  int* base   = (int*)p;  p += (size_t)(NSB + 8) * 4;
  int* ptr    = (int*)p;  p += (size_t)(N_NODES + 8) * 4;       // 400 KB

  // ---- build: sb hist -> scan -> sb scatter -> in-sb node sort ----
  hipMemsetAsync(hist, 0, (size_t)NSB * HPAD * 4, stream);
  hist_kernel<<<NCHUNK, 256, 0, stream>>>(dst, hist);
  scanb_kernel<<<1, 256, 0, stream>>>(hist, base, cursor, ptr);
  scatter_kernel<<<NCHUNK, 256, 0, stream>>>(dst, src, ew, cursor, packed1);
  sortsb_kernel<<<NSB, 256, 0, stream>>>(base, packed1, packed2, ptr);

  // ---- layer 1 GEMM via MFMA (bf16 h) ----
  gemm1_mfma_kernel<<<GRID1, 256, 0, stream>>>(x, W1, h);

  // ---- SPMM1: h_agg = relu(A @ h)  (h_agg overwrites dead packed1) ----
  spmm_kernel<1><<<N_NODES / 4, 256, 0, stream>>>(
      ptr, packed2, (const char*)h, h_agg);

  // ---- SPMM2: agg2 = A @ h_agg  (agg2 overwrites dead h) ----
  spmm_kernel<0><<<N_NODES / 4, 256, 0, stream>>>(
      ptr, packed2, (const char*)h_agg, agg2);

  // ---- out = log_softmax(agg2 @ W2) ----
  gemm2_lsm_kernel<<<(N_NODES + 255) / 256, 256, 0, stream>>>(
      (const __hip_bfloat16*)agg2, W2, out);
}

// Round 3
// 341.230 us; speedup vs baseline: 1.5455x; 1.1261x over previous
//
#include <hip/hip_runtime.h>
#include <hip/hip_bf16.h>
#include <math.h>

#define N_NODES 100000
#define N_EDGES 3200000
#define DIM_IN  128
#define DIM_HID 64
#define DIM_OUT 40

#define SBSHIFT 8
#define SBNODES 256                                  // nodes per super-bucket
#define NSB ((N_NODES + SBNODES - 1) / SBNODES)      // 391
#define HPAD  16                                     // counter stride: 64 B
#define CHUNK 12500                                  // 256 WGs exactly
#define NCHUNK (N_EDGES / CHUNK)                     // 256
#define GRID1 512                                    // gemm1 blocks

typedef int v2i  __attribute__((ext_vector_type(2)));
typedef int v16i __attribute__((ext_vector_type(16)));
typedef short bf16x8 __attribute__((ext_vector_type(8)));
typedef float f32x4  __attribute__((ext_vector_type(4)));

__device__ inline unsigned short f32_to_bf16_rne(float f) {
  const unsigned u = __float_as_uint(f);
  return (unsigned short)((u + 0x7FFFu + ((u >> 16) & 1u)) >> 16);
}

// ---- hist: per-WG LDS histogram of dst>>8 -> global totals + per-WG counts -
// 1024 threads, grid = 256 (1 WG/CU), int4-vectorized dst loads.
__global__ __launch_bounds__(1024) void hist_kernel(
    const int* __restrict__ dst, int* __restrict__ hist,
    int* __restrict__ cnt_wg) {
  __shared__ int cnt[NSB];
  const int t = threadIdx.x;
  for (int i = t; i < NSB; i += 1024) cnt[i] = 0;
  __syncthreads();
  const int e0 = blockIdx.x * CHUNK;
  for (int k = t; k < CHUNK / 4; k += 1024) {
    const int4 d4 = *(const int4*)(dst + e0 + 4 * k);
    atomicAdd(&cnt[d4.x >> SBSHIFT], 1);
    atomicAdd(&cnt[d4.y >> SBSHIFT], 1);
    atomicAdd(&cnt[d4.z >> SBSHIFT], 1);
    atomicAdd(&cnt[d4.w >> SBSHIFT], 1);
  }
  __syncthreads();
  int* cw = cnt_wg + blockIdx.x * NSB;
  for (int i = t; i < NSB; i += 1024) {
    const int c = cnt[i];
    cw[i] = c;                                   // per-WG count for scatter
    if (c) atomicAdd(&hist[i * HPAD], c);
  }
}

// ---- exclusive scan of 391 super-bucket counts (single block) --------------
__global__ __launch_bounds__(256) void scanb_kernel(
    const int* __restrict__ hist, int* __restrict__ base,
    int* __restrict__ cursor, int* __restrict__ ptr) {
  const int t = threadIdx.x;
  const int i0 = 2 * t, i1 = 2 * t + 1;
  const int v0 = (i0 < NSB) ? hist[i0 * HPAD] : 0;
  const int v1 = (i1 < NSB) ? hist[i1 * HPAD] : 0;
  const int s = v0 + v1;
  const int lane = t & 63, wid = t >> 6;
  int incl = s;
#pragma unroll
  for (int off = 1; off < 64; off <<= 1) {
    int n = __shfl_up(incl, off);
    if (lane >= off) incl += n;
  }
  __shared__ int wsum[4];
  if (lane == 63) wsum[wid] = incl;
  __syncthreads();
  int woff = 0;
  for (int k = 0; k < wid; ++k) woff += wsum[k];
  int run = woff + incl - s;
  if (i0 < NSB) { base[i0] = run; cursor[i0 * HPAD] = run; }
  run += v0;
  if (i1 < NSB) { base[i1] = run; cursor[i1 * HPAD] = run; }
  if (t == 255) { base[NSB] = N_EDGES; ptr[N_NODES] = N_EDGES; }
}

// ---- scatter: edges -> super-bucket regions ------------------------------
// No re-count: reservation sizes come from cnt_wg. 1024 threads, grid 256,
// int4/float4 loads. ~32-edge (256 B) contiguous segments per (WG,sb).
__global__ __launch_bounds__(1024) void scatter_kernel(
    const int* __restrict__ dst, const int* __restrict__ src,
    const float* __restrict__ ew, const int* __restrict__ cnt_wg,
    int* __restrict__ cursor, int2* __restrict__ packed1) {
  __shared__ int cnt[NSB];
  const int t = threadIdx.x;
  const int* cw = cnt_wg + blockIdx.x * NSB;
  for (int i = t; i < NSB; i += 1024) {
    const int c = cw[i];
    cnt[i] = c ? atomicAdd(&cursor[i * HPAD], c) : 0;   // cnt becomes cursor
  }
  __syncthreads();
  const int e0 = blockIdx.x * CHUNK;
  for (int k = t; k < CHUNK / 4; k += 1024) {
    const int e = e0 + 4 * k;
    const int4   d4 = *(const int4*)(dst + e);
    const int4   s4 = *(const int4*)(src + e);
    const float4 w4 = *(const float4*)(ew + e);
    int pos;
    pos = atomicAdd(&cnt[d4.x >> SBSHIFT], 1);
    packed1[pos] = make_int2(((d4.x & (SBNODES - 1)) << 20) | s4.x,
                             __float_as_int(w4.x));
    pos = atomicAdd(&cnt[d4.y >> SBSHIFT], 1);
    packed1[pos] = make_int2(((d4.y & (SBNODES - 1)) << 20) | s4.y,
                             __float_as_int(w4.y));
    pos = atomicAdd(&cnt[d4.z >> SBSHIFT], 1);
    packed1[pos] = make_int2(((d4.z & (SBNODES - 1)) << 20) | s4.z,
                             __float_as_int(w4.z));
    pos = atomicAdd(&cnt[d4.w >> SBSHIFT], 1);
    packed1[pos] = make_int2(((d4.w & (SBNODES - 1)) << 20) | s4.w,
                             __float_as_int(w4.w));
  }
}

// ---- pass 2: sort each super-bucket to node order; emit ptr ---------------
// 1024 threads (8 edges/thread). packed2.x stores src*128 (row byte offset).
__global__ __launch_bounds__(1024) void sortsb_kernel(
    const int* __restrict__ base, const int2* __restrict__ packed1,
    int2* __restrict__ packed2, int* __restrict__ ptr) {
  __shared__ int cnt[SBNODES];
  __shared__ int cur[SBNODES];
  __shared__ int wsum[4];
  const int t = threadIdx.x;
  const int b = blockIdx.x;
  if (t < SBNODES) cnt[t] = 0;
  const int e0 = base[b], e1 = base[b + 1];
  __syncthreads();
  for (int e = e0 + t; e < e1; e += 1024)
    atomicAdd(&cnt[(packed1[e].x >> 20) & (SBNODES - 1)], 1);
  __syncthreads();
  if (t < 256) {
    const int lane = t & 63, wid = t >> 6;
    const int v = cnt[t];
    int incl = v;
#pragma unroll
    for (int off = 1; off < 64; off <<= 1) {
      int n = __shfl_up(incl, off);
      if (lane >= off) incl += n;
    }
    if (lane == 63) wsum[wid] = incl;
    cur[t] = incl - v;                 // exclusive-within-wave, stash
  }
  __syncthreads();
  if (t < 256) {
    const int wid = t >> 6;
    int woff = 0;
    for (int k = 0; k < wid; ++k) woff += wsum[k];
    const int start = e0 + woff + cur[t];
    cur[t] = start;
    const int node = (b << SBSHIFT) + t;
    if (node < N_NODES) ptr[node] = start;
  }
  __syncthreads();
  for (int e = e0 + t; e < e1; e += 1024) {
    const int2 p = packed1[e];
    const int pos = atomicAdd(&cur[(p.x >> 20) & (SBNODES - 1)], 1);
    packed2[pos] = make_int2((p.x & 0xFFFFF) << 7, p.y);
  }
}

// ---- GEMM1 via MFMA: h = bf16(x @ W1) -------------------------------------
__global__ __launch_bounds__(256) void gemm1_mfma_kernel(
    const float* __restrict__ x, const float* __restrict__ W1,
    unsigned short* __restrict__ h) {
  __shared__ float wlds[DIM_IN * DIM_HID];   // 32 KB
  for (int i = threadIdx.x; i < DIM_IN * DIM_HID; i += 256) wlds[i] = W1[i];
  __syncthreads();
  const int lane = threadIdx.x & 63;
  const int wid = threadIdx.x >> 6;
  const int r16 = lane & 15;    // A row / B col within tile
  const int kg = lane >> 4;     // k-group of 8

  bf16x8 bf[4][4];              // [kc][nt]
#pragma unroll
  for (int kc = 0; kc < 4; ++kc)
#pragma unroll
    for (int nt = 0; nt < 4; ++nt)
#pragma unroll
      for (int j = 0; j < 8; ++j)
        bf[kc][nt][j] = (short)f32_to_bf16_rne(
            wlds[(kc * 32 + kg * 8 + j) * DIM_HID + nt * 16 + r16]);

  const int wglobal = blockIdx.x * 4 + wid;
  for (int tile = wglobal; tile < N_NODES / 16; tile += GRID1 * 4) {
    const float* xr = x + (size_t)(tile * 16 + r16) * DIM_IN + kg * 8;
    bf16x8 af[4];
#pragma unroll
    for (int kc = 0; kc < 4; ++kc) {
      const float4 v0 = *(const float4*)(xr + kc * 32);
      const float4 v1 = *(const float4*)(xr + kc * 32 + 4);
      af[kc][0] = (short)f32_to_bf16_rne(v0.x);
      af[kc][1] = (short)f32_to_bf16_rne(v0.y);
      af[kc][2] = (short)f32_to_bf16_rne(v0.z);
      af[kc][3] = (short)f32_to_bf16_rne(v0.w);
      af[kc][4] = (short)f32_to_bf16_rne(v1.x);
      af[kc][5] = (short)f32_to_bf16_rne(v1.y);
      af[kc][6] = (short)f32_to_bf16_rne(v1.z);
      af[kc][7] = (short)f32_to_bf16_rne(v1.w);
    }
    f32x4 acc[4];
#pragma unroll
    for (int nt = 0; nt < 4; ++nt) acc[nt] = (f32x4){0.f, 0.f, 0.f, 0.f};
#pragma unroll
    for (int kc = 0; kc < 4; ++kc)
#pragma unroll
      for (int nt = 0; nt < 4; ++nt)
        acc[nt] = __builtin_amdgcn_mfma_f32_16x16x32_bf16(
            af[kc], bf[kc][nt], acc[nt], 0, 0, 0);
    unsigned short* hr = h + (size_t)tile * 16 * DIM_HID;
#pragma unroll
    for (int nt = 0; nt < 4; ++nt)
#pragma unroll
      for (int r = 0; r < 4; ++r)
        hr[(kg * 4 + r) * DIM_HID + nt * 16 + r16] = f32_to_bf16_rne(acc[nt][r]);
  }
}

// ---- SPMM: one wave per node, one dim per lane, scalar edge data -----------
template <int RELU>
__global__ __launch_bounds__(256) void spmm_kernel(
    const int* __restrict__ ptr, const int2* __restrict__ packed,
    const char* __restrict__ hsrc, unsigned short* __restrict__ hout) {
  const int wv = __builtin_amdgcn_readfirstlane(threadIdx.x) >> 6;  // scalar
  const int node = blockIdx.x * 4 + wv;                 // 25000*4 == N
  const int lane = threadIdx.x & 63;
  v2i pp;
  asm volatile("s_load_dwordx2 %0, %1, 0x0\n\ts_waitcnt lgkmcnt(0)"
               : "=s"(pp) : "s"(ptr + node));
  const int eb = pp[0];
  const int deg = pp[1] - pp[0];
  const int2* pk = packed + eb;
  float acc = 0.f;
  int i = 0;
  for (; i + 8 <= deg; i += 8) {
    v16i q;
    asm volatile("s_load_dwordx16 %0, %1, 0x0\n\ts_waitcnt lgkmcnt(0)"
                 : "=s"(q) : "s"(pk + i));
#pragma unroll
    for (int j = 0; j < 8; ++j) {
      const unsigned short* rp =
          (const unsigned short*)(hsrc + (unsigned)q[2 * j]);
      const float wgt = __int_as_float(q[2 * j + 1]);
      acc = fmaf(wgt, __uint_as_float((unsigned)rp[lane] << 16), acc);
    }
  }
  if (i < deg) {                       // one predicated tail block (scalar)
    v16i q;
    asm volatile("s_load_dwordx16 %0, %1, 0x0\n\ts_waitcnt lgkmcnt(0)"
                 : "=s"(q) : "s"(pk + i));
#pragma unroll
    for (int j = 0; j < 8; ++j) {
      const bool val = (i + j) < deg;
      const int off = val ? q[2 * j] : 0;
      const float wgt = val ? __int_as_float(q[2 * j + 1]) : 0.f;
      const unsigned short* rp = (const unsigned short*)(hsrc + (unsigned)off);
      acc = fmaf(wgt, __uint_as_float((unsigned)rp[lane] << 16), acc);
    }
  }
  if (RELU) acc = fmaxf(acc, 0.f);
  hout[((size_t)node << 6) + lane] = f32_to_bf16_rne(acc);
}

// ---- final: out = log_softmax(agg2 @ W2), one node per thread --------------
__global__ __launch_bounds__(256) void gemm2_lsm_kernel(
    const __hip_bfloat16* __restrict__ agg2, const float* __restrict__ W2,
    float* __restrict__ out) {
  __shared__ float w2[DIM_HID * DIM_OUT];   // 10 KB, [k][c]
  for (int i = threadIdx.x; i < DIM_HID * DIM_OUT; i += 256) w2[i] = W2[i];
  __syncthreads();
  const int node = blockIdx.x * 256 + threadIdx.x;
  if (node >= N_NODES) return;
  const int4* rp = (const int4*)(agg2 + (size_t)node * 64);
  float sc[DIM_OUT];
#pragma unroll
  for (int c = 0; c < DIM_OUT; ++c) sc[c] = 0.f;
#pragma unroll
  for (int t = 0; t < 8; ++t) {
    const int4 v = rp[t];                       // 8 bf16 of the row
    const unsigned uu[4] = {(unsigned)v.x, (unsigned)v.y,
                            (unsigned)v.z, (unsigned)v.w};
#pragma unroll
    for (int p = 0; p < 4; ++p) {
      const float f0 = __uint_as_float(uu[p] << 16);
      const float f1 = __uint_as_float(uu[p] & 0xFFFF0000u);
      const int k = t * 8 + p * 2;
      const float4* wa = (const float4*)&w2[k * DIM_OUT];        // broadcast
      const float4* wb = (const float4*)&w2[(k + 1) * DIM_OUT];  // broadcast
#pragma unroll
      for (int q4 = 0; q4 < DIM_OUT / 4; ++q4) {
        const float4 a = wa[q4], b = wb[q4];
        sc[4 * q4 + 0] = fmaf(f0, a.x, fmaf(f1, b.x, sc[4 * q4 + 0]));
        sc[4 * q4 + 1] = fmaf(f0, a.y, fmaf(f1, b.y, sc[4 * q4 + 1]));
        sc[4 * q4 + 2] = fmaf(f0, a.z, fmaf(f1, b.z, sc[4 * q4 + 2]));
        sc[4 * q4 + 3] = fmaf(f0, a.w, fmaf(f1, b.w, sc[4 * q4 + 3]));
      }
    }
  }
  float m = sc[0];
#pragma unroll
  for (int c = 1; c < DIM_OUT; ++c) m = fmaxf(m, sc[c]);
  float s = 0.f;
#pragma unroll
  for (int c = 0; c < DIM_OUT; ++c) s += __expf(sc[c] - m);
  const float ls = __logf(s) + m;
  float4* op = (float4*)(out + (size_t)node * DIM_OUT);
#pragma unroll
  for (int t = 0; t < DIM_OUT / 4; ++t) {
    float4 o;
    o.x = sc[4 * t + 0] - ls;
    o.y = sc[4 * t + 1] - ls;
    o.z = sc[4 * t + 2] - ls;
    o.w = sc[4 * t + 3] - ls;
    op[t] = o;
  }
}

extern "C" void kernel_launch(void* const* d_in, const int* in_sizes, int n_in,
                              void* d_out, int out_size, void* d_ws, size_t ws_size,
                              hipStream_t stream) {
  const float* x  = (const float*)d_in[0];
  const int*   ei = (const int*)d_in[1];   // [2, E]: first E = dst, next E = src
  const float* ew = (const float*)d_in[2];
  const float* W1 = (const float*)d_in[3];
  const float* W2 = (const float*)d_in[4];
  float* out = (float*)d_out;

  const int* dst = ei;
  const int* src = ei + N_EDGES;

  // ---- workspace layout (regions reused once dead) ----
  // region0: packed1 (build) -> h_agg bf16 [N][64] (after sortsb)
  // region1: packed2 (+pad)
  // region2: h bf16 [N][64] (gemm1 out) -> agg2 bf16 [N][64] (after spmm1)
  char* p = (char*)d_ws;
  int2*           packed1 = (int2*)p;
  unsigned short* h_agg   = (unsigned short*)p;   // 12.8 MB of the 25.6
  p += (size_t)N_EDGES * 8;                                     // 25.6 MB
  int2* packed2 = (int2*)p;  p += (size_t)(N_EDGES + 16) * 8;   // 25.6 MB + pad
  unsigned short* h = (unsigned short*)p;
  unsigned short* agg2 = (unsigned short*)p;      // reuses h after spmm1
  p += (size_t)N_NODES * DIM_HID * 2;                           // 12.8 MB
  int* hist   = (int*)p;  p += (size_t)NSB * HPAD * 4;          // 25 KB
  int* cursor = (int*)p;  p += (size_t)NSB * HPAD * 4;          // 25 KB
  int* base   = (int*)p;  p += (size_t)(NSB + 8) * 4;
  int* ptr    = (int*)p;  p += (size_t)(N_NODES + 8) * 4;       // 400 KB
  int* cnt_wg = (int*)p;  p += (size_t)NCHUNK * NSB * 4;        // 400 KB

  // ---- build: sb hist -> scan -> sb scatter -> in-sb node sort ----
  hipMemsetAsync(hist, 0, (size_t)NSB * HPAD * 4, stream);
  hist_kernel<<<NCHUNK, 1024, 0, stream>>>(dst, hist, cnt_wg);
  scanb_kernel<<<1, 256, 0, stream>>>(hist, base, cursor, ptr);
  scatter_kernel<<<NCHUNK, 1024, 0, stream>>>(dst, src, ew, cnt_wg, cursor, packed1);
  sortsb_kernel<<<NSB, 1024, 0, stream>>>(base, packed1, packed2, ptr);

  // ---- layer 1 GEMM via MFMA (bf16 h) ----
  gemm1_mfma_kernel<<<GRID1, 256, 0, stream>>>(x, W1, h);

  // ---- SPMM1: h_agg = relu(A @ h)  (h_agg overwrites dead packed1) ----
  spmm_kernel<1><<<N_NODES / 4, 256, 0, stream>>>(
      ptr, packed2, (const char*)h, h_agg);

  // ---- SPMM2: agg2 = A @ h_agg  (agg2 overwrites dead h) ----
  spmm_kernel<0><<<N_NODES / 4, 256, 0, stream>>>(
      ptr, packed2, (const char*)h_agg, agg2);

  // ---- out = log_softmax(agg2 @ W2) ----
  gemm2_lsm_kernel<<<(N_NODES + 255) / 256, 256, 0, stream>>>(
      (const __hip_bfloat16*)agg2, W2, out);
}

// Round 5
// 326.706 us; speedup vs baseline: 1.6142x; 1.0445x over previous
//
#include <hip/hip_runtime.h>
#include <hip/hip_bf16.h>
#include <math.h>

#define N_NODES 100000
#define N_EDGES 3200000
#define DIM_IN  128
#define DIM_HID 64
#define DIM_OUT 40

#define SBSHIFT 8
#define SBNODES 256                                  // nodes per super-bucket
#define NSB ((N_NODES + SBNODES - 1) / SBNODES)      // 391
#define HPAD  16                                     // counter stride: 64 B
#define CHUNK 12500                                  // 256 WGs exactly
#define NCHUNK (N_EDGES / CHUNK)                     // 256
#define GRID1 512                                    // gemm1 blocks

typedef int v2i  __attribute__((ext_vector_type(2)));
typedef int v16i __attribute__((ext_vector_type(16)));
typedef short bf16x8 __attribute__((ext_vector_type(8)));
typedef float f32x4  __attribute__((ext_vector_type(4)));

__device__ inline unsigned short f32_to_bf16_rne(float f) {
  const unsigned u = __float_as_uint(f);
  return (unsigned short)((u + 0x7FFFu + ((u >> 16) & 1u)) >> 16);
}

// ---- hist: per-WG LDS histogram of dst>>8 -> global totals + per-WG counts -
__global__ __launch_bounds__(1024) void hist_kernel(
    const int* __restrict__ dst, int* __restrict__ hist,
    int* __restrict__ cnt_wg) {
  __shared__ int cnt[NSB];
  const int t = threadIdx.x;
  for (int i = t; i < NSB; i += 1024) cnt[i] = 0;
  __syncthreads();
  const int e0 = blockIdx.x * CHUNK;
  for (int k = t; k < CHUNK / 4; k += 1024) {
    const int4 d4 = *(const int4*)(dst + e0 + 4 * k);
    atomicAdd(&cnt[d4.x >> SBSHIFT], 1);
    atomicAdd(&cnt[d4.y >> SBSHIFT], 1);
    atomicAdd(&cnt[d4.z >> SBSHIFT], 1);
    atomicAdd(&cnt[d4.w >> SBSHIFT], 1);
  }
  __syncthreads();
  int* cw = cnt_wg + blockIdx.x * NSB;
  for (int i = t; i < NSB; i += 1024) {
    const int c = cnt[i];
    cw[i] = c;                                   // per-WG count for scatter
    if (c) atomicAdd(&hist[i * HPAD], c);
  }
}

// ---- exclusive scan of 391 super-bucket counts (single block) --------------
__global__ __launch_bounds__(256) void scanb_kernel(
    const int* __restrict__ hist, int* __restrict__ base,
    int* __restrict__ cursor, int* __restrict__ ptr) {
  const int t = threadIdx.x;
  const int i0 = 2 * t, i1 = 2 * t + 1;
  const int v0 = (i0 < NSB) ? hist[i0 * HPAD] : 0;
  const int v1 = (i1 < NSB) ? hist[i1 * HPAD] : 0;
  const int s = v0 + v1;
  const int lane = t & 63, wid = t >> 6;
  int incl = s;
#pragma unroll
  for (int off = 1; off < 64; off <<= 1) {
    int n = __shfl_up(incl, off);
    if (lane >= off) incl += n;
  }
  __shared__ int wsum[4];
  if (lane == 63) wsum[wid] = incl;
  __syncthreads();
  int woff = 0;
  for (int k = 0; k < wid; ++k) woff += wsum[k];
  int run = woff + incl - s;
  if (i0 < NSB) { base[i0] = run; cursor[i0 * HPAD] = run; }
  run += v0;
  if (i1 < NSB) { base[i1] = run; cursor[i1 * HPAD] = run; }
  if (t == 255) { base[NSB] = N_EDGES; ptr[N_NODES] = N_EDGES; }
}

// ---- scatter: edges -> super-bucket regions ------------------------------
__global__ __launch_bounds__(1024) void scatter_kernel(
    const int* __restrict__ dst, const int* __restrict__ src,
    const float* __restrict__ ew, const int* __restrict__ cnt_wg,
    int* __restrict__ cursor, int2* __restrict__ packed1) {
  __shared__ int cnt[NSB];
  const int t = threadIdx.x;
  const int* cw = cnt_wg + blockIdx.x * NSB;
  for (int i = t; i < NSB; i += 1024) {
    const int c = cw[i];
    cnt[i] = c ? atomicAdd(&cursor[i * HPAD], c) : 0;   // cnt becomes cursor
  }
  __syncthreads();
  const int e0 = blockIdx.x * CHUNK;
  for (int k = t; k < CHUNK / 4; k += 1024) {
    const int e = e0 + 4 * k;
    const int4   d4 = *(const int4*)(dst + e);
    const int4   s4 = *(const int4*)(src + e);
    const float4 w4 = *(const float4*)(ew + e);
    int pos;
    pos = atomicAdd(&cnt[d4.x >> SBSHIFT], 1);
    packed1[pos] = make_int2(((d4.x & (SBNODES - 1)) << 20) | s4.x,
                             __float_as_int(w4.x));
    pos = atomicAdd(&cnt[d4.y >> SBSHIFT], 1);
    packed1[pos] = make_int2(((d4.y & (SBNODES - 1)) << 20) | s4.y,
                             __float_as_int(w4.y));
    pos = atomicAdd(&cnt[d4.z >> SBSHIFT], 1);
    packed1[pos] = make_int2(((d4.z & (SBNODES - 1)) << 20) | s4.z,
                             __float_as_int(w4.z));
    pos = atomicAdd(&cnt[d4.w >> SBSHIFT], 1);
    packed1[pos] = make_int2(((d4.w & (SBNODES - 1)) << 20) | s4.w,
                             __float_as_int(w4.w));
  }
}

// ---- pass 2: sort each super-bucket to node order; emit ptr ---------------
__global__ __launch_bounds__(1024) void sortsb_kernel(
    const int* __restrict__ base, const int2* __restrict__ packed1,
    int2* __restrict__ packed2, int* __restrict__ ptr) {
  __shared__ int cnt[SBNODES];
  __shared__ int cur[SBNODES];
  __shared__ int wsum[4];
  const int t = threadIdx.x;
  const int b = blockIdx.x;
  if (t < SBNODES) cnt[t] = 0;
  const int e0 = base[b], e1 = base[b + 1];
  __syncthreads();
  for (int e = e0 + t; e < e1; e += 1024)
    atomicAdd(&cnt[(packed1[e].x >> 20) & (SBNODES - 1)], 1);
  __syncthreads();
  if (t < 256) {
    const int lane = t & 63, wid = t >> 6;
    const int v = cnt[t];
    int incl = v;
#pragma unroll
    for (int off = 1; off < 64; off <<= 1) {
      int n = __shfl_up(incl, off);
      if (lane >= off) incl += n;
    }
    if (lane == 63) wsum[wid] = incl;
    cur[t] = incl - v;                 // exclusive-within-wave, stash
  }
  __syncthreads();
  if (t < 256) {
    const int wid = t >> 6;
    int woff = 0;
    for (int k = 0; k < wid; ++k) woff += wsum[k];
    const int start = e0 + woff + cur[t];
    cur[t] = start;
    const int node = (b << SBSHIFT) + t;
    if (node < N_NODES) ptr[node] = start;
  }
  __syncthreads();
  for (int e = e0 + t; e < e1; e += 1024) {
    const int2 p = packed1[e];
    const int pos = atomicAdd(&cur[(p.x >> 20) & (SBNODES - 1)], 1);
    packed2[pos] = make_int2((p.x & 0xFFFFF) << 7, p.y);
  }
}

// ---- GEMM1 via MFMA: h = bf16(x @ W1) -------------------------------------
__global__ __launch_bounds__(256) void gemm1_mfma_kernel(
    const float* __restrict__ x, const float* __restrict__ W1,
    unsigned short* __restrict__ h) {
  __shared__ float wlds[DIM_IN * DIM_HID];   // 32 KB
  for (int i = threadIdx.x; i < DIM_IN * DIM_HID; i += 256) wlds[i] = W1[i];
  __syncthreads();
  const int lane = threadIdx.x & 63;
  const int wid = threadIdx.x >> 6;
  const int r16 = lane & 15;    // A row / B col within tile
  const int kg = lane >> 4;     // k-group of 8

  bf16x8 bf[4][4];              // [kc][nt]
#pragma unroll
  for (int kc = 0; kc < 4; ++kc)
#pragma unroll
    for (int nt = 0; nt < 4; ++nt)
#pragma unroll
      for (int j = 0; j < 8; ++j)
        bf[kc][nt][j] = (short)f32_to_bf16_rne(
            wlds[(kc * 32 + kg * 8 + j) * DIM_HID + nt * 16 + r16]);

  const int wglobal = blockIdx.x * 4 + wid;
  for (int tile = wglobal; tile < N_NODES / 16; tile += GRID1 * 4) {
    const float* xr = x + (size_t)(tile * 16 + r16) * DIM_IN + kg * 8;
    bf16x8 af[4];
#pragma unroll
    for (int kc = 0; kc < 4; ++kc) {
      const float4 v0 = *(const float4*)(xr + kc * 32);
      const float4 v1 = *(const float4*)(xr + kc * 32 + 4);
      af[kc][0] = (short)f32_to_bf16_rne(v0.x);
      af[kc][1] = (short)f32_to_bf16_rne(v0.y);
      af[kc][2] = (short)f32_to_bf16_rne(v0.z);
      af[kc][3] = (short)f32_to_bf16_rne(v0.w);
      af[kc][4] = (short)f32_to_bf16_rne(v1.x);
      af[kc][5] = (short)f32_to_bf16_rne(v1.y);
      af[kc][6] = (short)f32_to_bf16_rne(v1.z);
      af[kc][7] = (short)f32_to_bf16_rne(v1.w);
    }
    f32x4 acc[4];
#pragma unroll
    for (int nt = 0; nt < 4; ++nt) acc[nt] = (f32x4){0.f, 0.f, 0.f, 0.f};
#pragma unroll
    for (int kc = 0; kc < 4; ++kc)
#pragma unroll
      for (int nt = 0; nt < 4; ++nt)
        acc[nt] = __builtin_amdgcn_mfma_f32_16x16x32_bf16(
            af[kc], bf[kc][nt], acc[nt], 0, 0, 0);
    unsigned short* hr = h + (size_t)tile * 16 * DIM_HID;
#pragma unroll
    for (int nt = 0; nt < 4; ++nt)
#pragma unroll
      for (int r = 0; r < 4; ++r)
        hr[(kg * 4 + r) * DIM_HID + nt * 16 + r16] = f32_to_bf16_rne(acc[nt][r]);
  }
}

// ---- SPMM: one wave per node, one dim per lane, scalar edge data.
// SAFETY RULE (round-4 post-mortem): each s_load and its s_waitcnt live in
// the SAME asm block with "=s" outputs consumed only after — the allocator
// may copy loop-carried SGPR tuples, and a copy of a tuple with an in-flight
// s_load reads stale data. Stall amortization instead comes from WIDTH:
// 2x s_load_dwordx16 + one wait = 16 edges per drain (vs 8 in round 3).
template <int RELU>
__global__ __launch_bounds__(256) void spmm_kernel(
    const int* __restrict__ ptr, const int2* __restrict__ packed,
    const char* __restrict__ hsrc, unsigned short* __restrict__ hout) {
  const int wv = __builtin_amdgcn_readfirstlane(threadIdx.x) >> 6;  // scalar
  const int node = blockIdx.x * 4 + wv;                 // 25000*4 == N
  const int lane = threadIdx.x & 63;
  v2i pp;
  asm volatile("s_load_dwordx2 %0, %1, 0x0\n\ts_waitcnt lgkmcnt(0)"
               : "=s"(pp) : "s"(ptr + node));
  const int eb = pp[0];
  const int deg = pp[1] - pp[0];
  const int2* pk = packed + eb;
  float acc = 0.f;

  auto PROC = [&](const v16i& q) {
#pragma unroll
    for (int j = 0; j < 8; ++j) {
      const unsigned short* rp =
          (const unsigned short*)(hsrc + (unsigned)q[2 * j]);
      acc = fmaf(__int_as_float(q[2 * j + 1]),
                 __uint_as_float((unsigned)rp[lane] << 16), acc);
    }
  };
  auto PROCP = [&](const v16i& q, int i0) {   // predicated tail block
#pragma unroll
    for (int j = 0; j < 8; ++j) {
      const bool valid = (i0 + j) < deg;      // wave-uniform -> s_cselect
      const int off = valid ? q[2 * j] : 0;
      const float wgt = valid ? __int_as_float(q[2 * j + 1]) : 0.f;
      const unsigned short* rp = (const unsigned short*)(hsrc + (unsigned)off);
      acc = fmaf(wgt, __uint_as_float((unsigned)rp[lane] << 16), acc);
    }
  };

  int i = 0;
  for (; i + 16 <= deg; i += 16) {            // 16 edges per lgkm drain
    v16i q0, q1;
    asm volatile("s_load_dwordx16 %0, %2, 0x0\n\t"
                 "s_load_dwordx16 %1, %2, 0x40\n\t"
                 "s_waitcnt lgkmcnt(0)"
                 : "=s"(q0), "=s"(q1) : "s"(pk + i));
    PROC(q0);
    PROC(q1);
  }
  if (i + 8 <= deg) {                         // one full 8-block
    v16i q;
    asm volatile("s_load_dwordx16 %0, %1, 0x0\n\ts_waitcnt lgkmcnt(0)"
                 : "=s"(q) : "s"(pk + i));
    PROC(q);
    i += 8;
  }
  if (i < deg) {                              // one predicated tail block
    v16i q;
    asm volatile("s_load_dwordx16 %0, %1, 0x0\n\ts_waitcnt lgkmcnt(0)"
                 : "=s"(q) : "s"(pk + i));
    PROCP(q, i);
  }
  if (RELU) acc = fmaxf(acc, 0.f);
  hout[((size_t)node << 6) + lane] = f32_to_bf16_rne(acc);
}

// ---- final: out = log_softmax(agg2 @ W2), one node per thread --------------
__global__ __launch_bounds__(256) void gemm2_lsm_kernel(
    const __hip_bfloat16* __restrict__ agg2, const float* __restrict__ W2,
    float* __restrict__ out) {
  __shared__ float w2[DIM_HID * DIM_OUT];   // 10 KB, [k][c]
  for (int i = threadIdx.x; i < DIM_HID * DIM_OUT; i += 256) w2[i] = W2[i];
  __syncthreads();
  const int node = blockIdx.x * 256 + threadIdx.x;
  if (node >= N_NODES) return;
  const int4* rp = (const int4*)(agg2 + (size_t)node * 64);
  float sc[DIM_OUT];
#pragma unroll
  for (int c = 0; c < DIM_OUT; ++c) sc[c] = 0.f;
#pragma unroll
  for (int t = 0; t < 8; ++t) {
    const int4 v = rp[t];                       // 8 bf16 of the row
    const unsigned uu[4] = {(unsigned)v.x, (unsigned)v.y,
                            (unsigned)v.z, (unsigned)v.w};
#pragma unroll
    for (int p = 0; p < 4; ++p) {
      const float f0 = __uint_as_float(uu[p] << 16);
      const float f1 = __uint_as_float(uu[p] & 0xFFFF0000u);
      const int k = t * 8 + p * 2;
      const float4* wa = (const float4*)&w2[k * DIM_OUT];        // broadcast
      const float4* wb = (const float4*)&w2[(k + 1) * DIM_OUT];  // broadcast
#pragma unroll
      for (int q4 = 0; q4 < DIM_OUT / 4; ++q4) {
        const float4 a = wa[q4], b = wb[q4];
        sc[4 * q4 + 0] = fmaf(f0, a.x, fmaf(f1, b.x, sc[4 * q4 + 0]));
        sc[4 * q4 + 1] = fmaf(f0, a.y, fmaf(f1, b.y, sc[4 * q4 + 1]));
        sc[4 * q4 + 2] = fmaf(f0, a.z, fmaf(f1, b.z, sc[4 * q4 + 2]));
        sc[4 * q4 + 3] = fmaf(f0, a.w, fmaf(f1, b.w, sc[4 * q4 + 3]));
      }
    }
  }
  float m = sc[0];
#pragma unroll
  for (int c = 1; c < DIM_OUT; ++c) m = fmaxf(m, sc[c]);
  float s = 0.f;
#pragma unroll
  for (int c = 0; c < DIM_OUT; ++c) s += __expf(sc[c] - m);
  const float ls = __logf(s) + m;
  float4* op = (float4*)(out + (size_t)node * DIM_OUT);
#pragma unroll
  for (int t = 0; t < DIM_OUT / 4; ++t) {
    float4 o;
    o.x = sc[4 * t + 0] - ls;
    o.y = sc[4 * t + 1] - ls;
    o.z = sc[4 * t + 2] - ls;
    o.w = sc[4 * t + 3] - ls;
    op[t] = o;
  }
}

extern "C" void kernel_launch(void* const* d_in, const int* in_sizes, int n_in,
                              void* d_out, int out_size, void* d_ws, size_t ws_size,
                              hipStream_t stream) {
  const float* x  = (const float*)d_in[0];
  const int*   ei = (const int*)d_in[1];   // [2, E]: first E = dst, next E = src
  const float* ew = (const float*)d_in[2];
  const float* W1 = (const float*)d_in[3];
  const float* W2 = (const float*)d_in[4];
  float* out = (float*)d_out;

  const int* dst = ei;
  const int* src = ei + N_EDGES;

  // ---- workspace layout (regions reused once dead) ----
  // region0: packed1 (build) -> h_agg bf16 [N][64] (after sortsb)
  // region1: packed2 (+pad)
  // region2: h bf16 [N][64] (gemm1 out) -> agg2 bf16 [N][64] (after spmm1)
  char* p = (char*)d_ws;
  int2*           packed1 = (int2*)p;
  unsigned short* h_agg   = (unsigned short*)p;   // 12.8 MB of the 25.6
  p += (size_t)N_EDGES * 8;                                     // 25.6 MB
  int2* packed2 = (int2*)p;  p += (size_t)(N_EDGES + 32) * 8;   // 25.6 MB + pad
  unsigned short* h = (unsigned short*)p;
  unsigned short* agg2 = (unsigned short*)p;      // reuses h after spmm1
  p += (size_t)N_NODES * DIM_HID * 2;                           // 12.8 MB
  int* hist   = (int*)p;  p += (size_t)NSB * HPAD * 4;          // 25 KB
  int* cursor = (int*)p;  p += (size_t)NSB * HPAD * 4;          // 25 KB
  int* base   = (int*)p;  p += (size_t)(NSB + 8) * 4;
  int* ptr    = (int*)p;  p += (size_t)(N_NODES + 8) * 4;       // 400 KB
  int* cnt_wg = (int*)p;  p += (size_t)NCHUNK * NSB * 4;        // 400 KB

  // ---- build: sb hist -> scan -> sb scatter -> in-sb node sort ----
  hipMemsetAsync(hist, 0, (size_t)NSB * HPAD * 4, stream);
  hist_kernel<<<NCHUNK, 1024, 0, stream>>>(dst, hist, cnt_wg);
  scanb_kernel<<<1, 256, 0, stream>>>(hist, base, cursor, ptr);
  scatter_kernel<<<NCHUNK, 1024, 0, stream>>>(dst, src, ew, cnt_wg, cursor, packed1);
  sortsb_kernel<<<NSB, 1024, 0, stream>>>(base, packed1, packed2, ptr);

  // ---- layer 1 GEMM via MFMA (bf16 h) ----
  gemm1_mfma_kernel<<<GRID1, 256, 0, stream>>>(x, W1, h);

  // ---- SPMM1: h_agg = relu(A @ h)  (h_agg overwrites dead packed1) ----
  spmm_kernel<1><<<N_NODES / 4, 256, 0, stream>>>(
      ptr, packed2, (const char*)h, h_agg);

  // ---- SPMM2: agg2 = A @ h_agg  (agg2 overwrites dead h) ----
  spmm_kernel<0><<<N_NODES / 4, 256, 0, stream>>>(
      ptr, packed2, (const char*)h_agg, agg2);

  // ---- out = log_softmax(agg2 @ W2) ----
  gemm2_lsm_kernel<<<(N_NODES + 255) / 256, 256, 0, stream>>>(
      (const __hip_bfloat16*)agg2, W2, out);
}

// Round 6
// 310.435 us; speedup vs baseline: 1.6988x; 1.0524x over previous
//
#include <hip/hip_runtime.h>
#include <hip/hip_bf16.h>
#include <math.h>

#define N_NODES 100000
#define N_EDGES 3200000
#define DIM_IN  128
#define DIM_HID 64
#define DIM_OUT 40

#define SBSHIFT 8
#define SBNODES 256                                  // nodes per super-bucket
#define NSB ((N_NODES + SBNODES - 1) / SBNODES)      // 391
#define HPAD  16                                     // counter stride: 64 B
#define CHUNK 12500                                  // 256 WGs exactly
#define NCHUNK (N_EDGES / CHUNK)                     // 256
#define GRID1 512                                    // gemm1 blocks
#define NTILE2 (N_NODES / 16)                        // 6250 gemm2 tiles

typedef int v2i  __attribute__((ext_vector_type(2)));
typedef int v16i __attribute__((ext_vector_type(16)));
typedef short bf16x8 __attribute__((ext_vector_type(8)));
typedef float f32x4  __attribute__((ext_vector_type(4)));

__device__ inline unsigned short f32_to_bf16_rne(float f) {
  const unsigned u = __float_as_uint(f);
  return (unsigned short)((u + 0x7FFFu + ((u >> 16) & 1u)) >> 16);
}

// ---- hist: per-WG LDS histogram of dst>>8 -> global totals + per-WG counts -
__global__ __launch_bounds__(1024) void hist_kernel(
    const int* __restrict__ dst, int* __restrict__ hist,
    int* __restrict__ cnt_wg) {
  __shared__ int cnt[NSB];
  const int t = threadIdx.x;
  for (int i = t; i < NSB; i += 1024) cnt[i] = 0;
  __syncthreads();
  const int e0 = blockIdx.x * CHUNK;
  for (int k = t; k < CHUNK / 4; k += 1024) {
    const int4 d4 = *(const int4*)(dst + e0 + 4 * k);
    atomicAdd(&cnt[d4.x >> SBSHIFT], 1);
    atomicAdd(&cnt[d4.y >> SBSHIFT], 1);
    atomicAdd(&cnt[d4.z >> SBSHIFT], 1);
    atomicAdd(&cnt[d4.w >> SBSHIFT], 1);
  }
  __syncthreads();
  int* cw = cnt_wg + blockIdx.x * NSB;
  for (int i = t; i < NSB; i += 1024) {
    const int c = cnt[i];
    cw[i] = c;                                   // per-WG count for scatter
    if (c) atomicAdd(&hist[i * HPAD], c);
  }
}

// ---- exclusive scan of 391 super-bucket counts (single block) --------------
__global__ __launch_bounds__(256) void scanb_kernel(
    const int* __restrict__ hist, int* __restrict__ base,
    int* __restrict__ cursor, int* __restrict__ ptr) {
  const int t = threadIdx.x;
  const int i0 = 2 * t, i1 = 2 * t + 1;
  const int v0 = (i0 < NSB) ? hist[i0 * HPAD] : 0;
  const int v1 = (i1 < NSB) ? hist[i1 * HPAD] : 0;
  const int s = v0 + v1;
  const int lane = t & 63, wid = t >> 6;
  int incl = s;
#pragma unroll
  for (int off = 1; off < 64; off <<= 1) {
    int n = __shfl_up(incl, off);
    if (lane >= off) incl += n;
  }
  __shared__ int wsum[4];
  if (lane == 63) wsum[wid] = incl;
  __syncthreads();
  int woff = 0;
  for (int k = 0; k < wid; ++k) woff += wsum[k];
  int run = woff + incl - s;
  if (i0 < NSB) { base[i0] = run; cursor[i0 * HPAD] = run; }
  run += v0;
  if (i1 < NSB) { base[i1] = run; cursor[i1 * HPAD] = run; }
  if (t == 255) { base[NSB] = N_EDGES; ptr[N_NODES] = N_EDGES; }
}

// ---- scatter: edges -> super-bucket regions ------------------------------
__global__ __launch_bounds__(1024) void scatter_kernel(
    const int* __restrict__ dst, const int* __restrict__ src,
    const float* __restrict__ ew, const int* __restrict__ cnt_wg,
    int* __restrict__ cursor, int2* __restrict__ packed1) {
  __shared__ int cnt[NSB];
  const int t = threadIdx.x;
  const int* cw = cnt_wg + blockIdx.x * NSB;
  for (int i = t; i < NSB; i += 1024) {
    const int c = cw[i];
    cnt[i] = c ? atomicAdd(&cursor[i * HPAD], c) : 0;   // cnt becomes cursor
  }
  __syncthreads();
  const int e0 = blockIdx.x * CHUNK;
  for (int k = t; k < CHUNK / 4; k += 1024) {
    const int e = e0 + 4 * k;
    const int4   d4 = *(const int4*)(dst + e);
    const int4   s4 = *(const int4*)(src + e);
    const float4 w4 = *(const float4*)(ew + e);
    int pos;
    pos = atomicAdd(&cnt[d4.x >> SBSHIFT], 1);
    packed1[pos] = make_int2(((d4.x & (SBNODES - 1)) << 20) | s4.x,
                             __float_as_int(w4.x));
    pos = atomicAdd(&cnt[d4.y >> SBSHIFT], 1);
    packed1[pos] = make_int2(((d4.y & (SBNODES - 1)) << 20) | s4.y,
                             __float_as_int(w4.y));
    pos = atomicAdd(&cnt[d4.z >> SBSHIFT], 1);
    packed1[pos] = make_int2(((d4.z & (SBNODES - 1)) << 20) | s4.z,
                             __float_as_int(w4.z));
    pos = atomicAdd(&cnt[d4.w >> SBSHIFT], 1);
    packed1[pos] = make_int2(((d4.w & (SBNODES - 1)) << 20) | s4.w,
                             __float_as_int(w4.w));
  }
}

// ---- pass 2: sort each super-bucket to node order; emit ptr ---------------
__global__ __launch_bounds__(1024) void sortsb_kernel(
    const int* __restrict__ base, const int2* __restrict__ packed1,
    int2* __restrict__ packed2, int* __restrict__ ptr) {
  __shared__ int cnt[SBNODES];
  __shared__ int cur[SBNODES];
  __shared__ int wsum[4];
  const int t = threadIdx.x;
  const int b = blockIdx.x;
  if (t < SBNODES) cnt[t] = 0;
  const int e0 = base[b], e1 = base[b + 1];
  __syncthreads();
  for (int e = e0 + t; e < e1; e += 1024)
    atomicAdd(&cnt[(packed1[e].x >> 20) & (SBNODES - 1)], 1);
  __syncthreads();
  if (t < 256) {
    const int lane = t & 63, wid = t >> 6;
    const int v = cnt[t];
    int incl = v;
#pragma unroll
    for (int off = 1; off < 64; off <<= 1) {
      int n = __shfl_up(incl, off);
      if (lane >= off) incl += n;
    }
    if (lane == 63) wsum[wid] = incl;
    cur[t] = incl - v;                 // exclusive-within-wave, stash
  }
  __syncthreads();
  if (t < 256) {
    const int wid = t >> 6;
    int woff = 0;
    for (int k = 0; k < wid; ++k) woff += wsum[k];
    const int start = e0 + woff + cur[t];
    cur[t] = start;
    const int node = (b << SBSHIFT) + t;
    if (node < N_NODES) ptr[node] = start;
  }
  __syncthreads();
  for (int e = e0 + t; e < e1; e += 1024) {
    const int2 p = packed1[e];
    const int pos = atomicAdd(&cur[(p.x >> 20) & (SBNODES - 1)], 1);
    packed2[pos] = make_int2((p.x & 0xFFFFF) << 7, p.y);
  }
}

// ---- GEMM1 via MFMA: h = bf16(x @ W1) -------------------------------------
__global__ __launch_bounds__(256) void gemm1_mfma_kernel(
    const float* __restrict__ x, const float* __restrict__ W1,
    unsigned short* __restrict__ h) {
  __shared__ float wlds[DIM_IN * DIM_HID];   // 32 KB
  for (int i = threadIdx.x; i < DIM_IN * DIM_HID; i += 256) wlds[i] = W1[i];
  __syncthreads();
  const int lane = threadIdx.x & 63;
  const int wid = threadIdx.x >> 6;
  const int r16 = lane & 15;    // A row / B col within tile
  const int kg = lane >> 4;     // k-group of 8

  bf16x8 bf[4][4];              // [kc][nt]
#pragma unroll
  for (int kc = 0; kc < 4; ++kc)
#pragma unroll
    for (int nt = 0; nt < 4; ++nt)
#pragma unroll
      for (int j = 0; j < 8; ++j)
        bf[kc][nt][j] = (short)f32_to_bf16_rne(
            wlds[(kc * 32 + kg * 8 + j) * DIM_HID + nt * 16 + r16]);

  const int wglobal = blockIdx.x * 4 + wid;
  for (int tile = wglobal; tile < N_NODES / 16; tile += GRID1 * 4) {
    const float* xr = x + (size_t)(tile * 16 + r16) * DIM_IN + kg * 8;
    bf16x8 af[4];
#pragma unroll
    for (int kc = 0; kc < 4; ++kc) {
      const float4 v0 = *(const float4*)(xr + kc * 32);
      const float4 v1 = *(const float4*)(xr + kc * 32 + 4);
      af[kc][0] = (short)f32_to_bf16_rne(v0.x);
      af[kc][1] = (short)f32_to_bf16_rne(v0.y);
      af[kc][2] = (short)f32_to_bf16_rne(v0.z);
      af[kc][3] = (short)f32_to_bf16_rne(v0.w);
      af[kc][4] = (short)f32_to_bf16_rne(v1.x);
      af[kc][5] = (short)f32_to_bf16_rne(v1.y);
      af[kc][6] = (short)f32_to_bf16_rne(v1.z);
      af[kc][7] = (short)f32_to_bf16_rne(v1.w);
    }
    f32x4 acc[4];
#pragma unroll
    for (int nt = 0; nt < 4; ++nt) acc[nt] = (f32x4){0.f, 0.f, 0.f, 0.f};
#pragma unroll
    for (int kc = 0; kc < 4; ++kc)
#pragma unroll
      for (int nt = 0; nt < 4; ++nt)
        acc[nt] = __builtin_amdgcn_mfma_f32_16x16x32_bf16(
            af[kc], bf[kc][nt], acc[nt], 0, 0, 0);
    unsigned short* hr = h + (size_t)tile * 16 * DIM_HID;
#pragma unroll
    for (int nt = 0; nt < 4; ++nt)
#pragma unroll
      for (int r = 0; r < 4; ++r)
        hr[(kg * 4 + r) * DIM_HID + nt * 16 + r16] = f32_to_bf16_rne(acc[nt][r]);
  }
}

// ---- SPMM: one wave per node, one dim per lane, scalar edge data.
// SAFETY RULE (round-4 post-mortem): each s_load and its s_waitcnt live in
// the SAME asm block with "=s" outputs consumed only after — the allocator
// may copy loop-carried SGPR tuples, and a copy of a tuple with an in-flight
// s_load reads stale data. Stall amortization comes from WIDTH:
// 2x s_load_dwordx16 + one wait = 16 edges per drain.
template <int RELU>
__global__ __launch_bounds__(256) void spmm_kernel(
    const int* __restrict__ ptr, const int2* __restrict__ packed,
    const char* __restrict__ hsrc, unsigned short* __restrict__ hout) {
  const int wv = __builtin_amdgcn_readfirstlane(threadIdx.x) >> 6;  // scalar
  const int node = blockIdx.x * 4 + wv;                 // 25000*4 == N
  const int lane = threadIdx.x & 63;
  v2i pp;
  asm volatile("s_load_dwordx2 %0, %1, 0x0\n\ts_waitcnt lgkmcnt(0)"
               : "=s"(pp) : "s"(ptr + node));
  const int eb = pp[0];
  const int deg = pp[1] - pp[0];
  const int2* pk = packed + eb;
  float acc = 0.f;

  auto PROC = [&](const v16i& q) {
#pragma unroll
    for (int j = 0; j < 8; ++j) {
      const unsigned short* rp =
          (const unsigned short*)(hsrc + (unsigned)q[2 * j]);
      acc = fmaf(__int_as_float(q[2 * j + 1]),
                 __uint_as_float((unsigned)rp[lane] << 16), acc);
    }
  };
  auto PROCP = [&](const v16i& q, int i0) {   // predicated tail block
#pragma unroll
    for (int j = 0; j < 8; ++j) {
      const bool valid = (i0 + j) < deg;      // wave-uniform -> s_cselect
      const int off = valid ? q[2 * j] : 0;
      const float wgt = valid ? __int_as_float(q[2 * j + 1]) : 0.f;
      const unsigned short* rp = (const unsigned short*)(hsrc + (unsigned)off);
      acc = fmaf(wgt, __uint_as_float((unsigned)rp[lane] << 16), acc);
    }
  };

  int i = 0;
  for (; i + 16 <= deg; i += 16) {            // 16 edges per lgkm drain
    v16i q0, q1;
    asm volatile("s_load_dwordx16 %0, %2, 0x0\n\t"
                 "s_load_dwordx16 %1, %2, 0x40\n\t"
                 "s_waitcnt lgkmcnt(0)"
                 : "=s"(q0), "=s"(q1) : "s"(pk + i));
    PROC(q0);
    PROC(q1);
  }
  if (i + 8 <= deg) {                         // one full 8-block
    v16i q;
    asm volatile("s_load_dwordx16 %0, %1, 0x0\n\ts_waitcnt lgkmcnt(0)"
                 : "=s"(q) : "s"(pk + i));
    PROC(q);
    i += 8;
  }
  if (i < deg) {                              // one predicated tail block
    v16i q;
    asm volatile("s_load_dwordx16 %0, %1, 0x0\n\ts_waitcnt lgkmcnt(0)"
                 : "=s"(q) : "s"(pk + i));
    PROCP(q, i);
  }
  if (RELU) acc = fmaxf(acc, 0.f);
  hout[((size_t)node << 6) + lane] = f32_to_bf16_rne(acc);
}

// ---- final: out = log_softmax(agg2 @ W2) via MFMA --------------------------
// One wave per 16-node tile. W2 (bf16, cols>=40 zeroed) lives in 24 VGPRs as
// 6 B-frags built once; per tile: 2 int4 A-loads + 6 MFMA + in-register
// log-softmax. C/D map (verified in gemm1): col=lane&15, row=(lane>>4)*4+reg
// -> each node row spans an aligned 16-lane group; reduce with 4x shfl_xor.
__global__ __launch_bounds__(256) void gemm2_lsm_mfma_kernel(
    const unsigned short* __restrict__ agg2, const float* __restrict__ W2,
    float* __restrict__ out) {
  const int lane = threadIdx.x & 63;
  const int wid  = threadIdx.x >> 6;
  const int r16  = lane & 15;
  const int kg   = lane >> 4;
  const int tile = blockIdx.x * 4 + wid;
  if (tile >= NTILE2) return;

  bf16x8 bw[2][3];                      // [kc][nt]
#pragma unroll
  for (int kc = 0; kc < 2; ++kc)
#pragma unroll
    for (int nt = 0; nt < 3; ++nt) {
      const int c = nt * 16 + r16;
#pragma unroll
      for (int j = 0; j < 8; ++j) {
        const int k = kc * 32 + kg * 8 + j;
        const float v = (c < DIM_OUT) ? W2[k * DIM_OUT + c] : 0.f;
        bw[kc][nt][j] = (short)f32_to_bf16_rne(v);
      }
    }

  const int node0 = tile * 16;
  const bf16x8* ar = (const bf16x8*)(agg2 + (size_t)(node0 + r16) * 64);
  f32x4 acc[3];
#pragma unroll
  for (int nt = 0; nt < 3; ++nt) acc[nt] = (f32x4){0.f, 0.f, 0.f, 0.f};
#pragma unroll
  for (int kc = 0; kc < 2; ++kc) {
    const bf16x8 a = ar[kc * 4 + kg];   // 8 bf16 at k = kc*32 + kg*8
#pragma unroll
    for (int nt = 0; nt < 3; ++nt)
      acc[nt] = __builtin_amdgcn_mfma_f32_16x16x32_bf16(a, bw[kc][nt],
                                                        acc[nt], 0, 0, 0);
  }
  const bool c2ok = (r16 < DIM_OUT - 32);          // cols 32..39 valid
#pragma unroll
  for (int r = 0; r < 4; ++r) {
    float m = fmaxf(acc[0][r], acc[1][r]);
    m = fmaxf(m, c2ok ? acc[2][r] : -INFINITY);
#pragma unroll
    for (int off = 1; off < 16; off <<= 1) m = fmaxf(m, __shfl_xor(m, off));
    float e = __expf(acc[0][r] - m) + __expf(acc[1][r] - m) +
              (c2ok ? __expf(acc[2][r] - m) : 0.f);
#pragma unroll
    for (int off = 1; off < 16; off <<= 1) e += __shfl_xor(e, off);
    const float ls = __logf(e) + m;
    float* orow = out + (size_t)(node0 + kg * 4 + r) * DIM_OUT;
    orow[r16]      = acc[0][r] - ls;
    orow[16 + r16] = acc[1][r] - ls;
    if (c2ok) orow[32 + r16] = acc[2][r] - ls;
  }
}

extern "C" void kernel_launch(void* const* d_in, const int* in_sizes, int n_in,
                              void* d_out, int out_size, void* d_ws, size_t ws_size,
                              hipStream_t stream) {
  const float* x  = (const float*)d_in[0];
  const int*   ei = (const int*)d_in[1];   // [2, E]: first E = dst, next E = src
  const float* ew = (const float*)d_in[2];
  const float* W1 = (const float*)d_in[3];
  const float* W2 = (const float*)d_in[4];
  float* out = (float*)d_out;

  const int* dst = ei;
  const int* src = ei + N_EDGES;

  // ---- workspace layout (regions reused once dead) ----
  // region0: packed1 (build) -> h_agg bf16 [N][64] (after sortsb)
  // region1: packed2 (+pad)
  // region2: h bf16 [N][64] (gemm1 out) -> agg2 bf16 [N][64] (after spmm1)
  char* p = (char*)d_ws;
  int2*           packed1 = (int2*)p;
  unsigned short* h_agg   = (unsigned short*)p;   // 12.8 MB of the 25.6
  p += (size_t)N_EDGES * 8;                                     // 25.6 MB
  int2* packed2 = (int2*)p;  p += (size_t)(N_EDGES + 32) * 8;   // 25.6 MB + pad
  unsigned short* h = (unsigned short*)p;
  unsigned short* agg2 = (unsigned short*)p;      // reuses h after spmm1
  p += (size_t)N_NODES * DIM_HID * 2;                           // 12.8 MB
  int* hist   = (int*)p;  p += (size_t)NSB * HPAD * 4;          // 25 KB
  int* cursor = (int*)p;  p += (size_t)NSB * HPAD * 4;          // 25 KB
  int* base   = (int*)p;  p += (size_t)(NSB + 8) * 4;
  int* ptr    = (int*)p;  p += (size_t)(N_NODES + 8) * 4;       // 400 KB
  int* cnt_wg = (int*)p;  p += (size_t)NCHUNK * NSB * 4;        // 400 KB

  // ---- build: sb hist -> scan -> sb scatter -> in-sb node sort ----
  hipMemsetAsync(hist, 0, (size_t)NSB * HPAD * 4, stream);
  hist_kernel<<<NCHUNK, 1024, 0, stream>>>(dst, hist, cnt_wg);
  scanb_kernel<<<1, 256, 0, stream>>>(hist, base, cursor, ptr);
  scatter_kernel<<<NCHUNK, 1024, 0, stream>>>(dst, src, ew, cnt_wg, cursor, packed1);
  sortsb_kernel<<<NSB, 1024, 0, stream>>>(base, packed1, packed2, ptr);

  // ---- layer 1 GEMM via MFMA (bf16 h) ----
  gemm1_mfma_kernel<<<GRID1, 256, 0, stream>>>(x, W1, h);

  // ---- SPMM1: h_agg = relu(A @ h)  (h_agg overwrites dead packed1) ----
  spmm_kernel<1><<<N_NODES / 4, 256, 0, stream>>>(
      ptr, packed2, (const char*)h, h_agg);

  // ---- SPMM2: agg2 = A @ h_agg  (agg2 overwrites dead h) ----
  spmm_kernel<0><<<N_NODES / 4, 256, 0, stream>>>(
      ptr, packed2, (const char*)h_agg, agg2);

  // ---- out = log_softmax(agg2 @ W2) via MFMA ----
  gemm2_lsm_mfma_kernel<<<(NTILE2 + 3) / 4, 256, 0, stream>>>(
      agg2, W2, out);
}